// Round 2
// baseline (466.799 us; speedup 1.0000x reference)
//
#include <hip/hip_runtime.h>

// BlockCirculantLinear via frequency domain:
//   out[s, o*128+t] = ifft_t( sum_j fft(x_d[s,j,:]) * conj(fft(W[o,j,:])) )
// K1:  DFT of x-blocks (MFMA GEMM vs cos/sin basis) -> X[f][s][jc] bf16
// K2a: per-frequency real-ified GEMM over jc (K=128), 4 f per block, packs
//      8 contiguous fc per lane -> Y[s*64+o][160] bf16 (16-B stores)
// K2b: inverse-DFT GEMM: out[row][t] = Y[row][:160] * B2T[t][:160], rows of Y
//      map exactly onto out rows -> coalesced fp32 stores.

typedef __bf16 bf16;
typedef __bf16 bf16x4 __attribute__((ext_vector_type(4)));
typedef __bf16 bf16x8 __attribute__((ext_vector_type(8)));
typedef float f32x4 __attribute__((ext_vector_type(4)));

#define PI_F 3.14159265358979323846f

// ws layout (bytes)
#define WS_B1   0u           // [192 fc][128 t] bf16 = 49152
#define WS_B2T  49152u       // [128 t][160 fc] bf16 = 40960
#define WS_WMAT 90112u       // [65 f][128 oc][128 jc] bf16 = 2129920
#define WS_X    2220032u     // [65 f][4096 s][128 jc] bf16 = 68157440
#define WS_Y    70377472ull  // [262144 rows][160 fc] bf16 = 83886080
#define WS_NEED 154263552ull

__device__ __forceinline__ unsigned int pack_bf2(float a, float b) {
    unsigned short ra = __builtin_bit_cast(unsigned short, (bf16)a);
    unsigned short rb = __builtin_bit_cast(unsigned short, (bf16)b);
    return (unsigned int)ra | ((unsigned int)rb << 16);
}

// ---------------- init: DFT bases ----------------
__global__ __launch_bounds__(256) void init_basis(bf16* __restrict__ B1,
                                                  bf16* __restrict__ B2T) {
    int gid = blockIdx.x * 256 + threadIdx.x;
    if (gid < 192 * 128) {
        int fc = gid >> 7, t = gid & 127;
        int f = fc >> 1;
        float v = 0.f;
        if (f <= 64) {
            int a = (f * t) & 127;
            float ang = a * (PI_F / 64.f);
            v = (fc & 1) ? -__sinf(ang) : __cosf(ang);
        }
        B1[gid] = (bf16)v;
    }
    if (gid < 128 * 160) {
        int t = gid / 160, fc = gid % 160;
        int f = fc >> 1, c = fc & 1;
        float v = 0.f;
        if (f == 0) {
            v = c ? 0.f : (1.f / 128.f);
        } else if (f == 64) {
            v = c ? 0.f : ((t & 1) ? -1.f / 128.f : 1.f / 128.f);
        } else if (f < 64) {
            int a = (f * t) & 127;
            float ang = a * (PI_F / 64.f);
            v = c ? (-2.f / 128.f) * __sinf(ang) : (2.f / 128.f) * __cosf(ang);
        }
        B2T[gid] = (bf16)v;
    }
}

// ---------------- init: frequency-domain weights ----------------
// One block per o. Stage W[o] (64 j x 128 tau) in LDS (pad 129 -> conflict-free),
// wave w computes f = fo*4+w for all 64 j.
__global__ __launch_bounds__(256) void init_wmat(const float* __restrict__ W,
                                                 bf16* __restrict__ Wm) {
    __shared__ float wrow[64 * 129];
    __shared__ float ct[128], st[128];
    const int tid = threadIdx.x;
    const int o = blockIdx.x;
    if (tid < 128) {
        float ang = tid * (PI_F / 64.f);
        ct[tid] = __cosf(ang);
        st[tid] = __sinf(ang);
    }
    for (int i = tid; i < 2048; i += 256) {
        float4 v = *(const float4*)(W + (size_t)o * 8192 + i * 4);
        int j = i >> 5, c = i & 31;
        float* d = &wrow[j * 129 + c * 4];
        d[0] = v.x; d[1] = v.y; d[2] = v.z; d[3] = v.w;
    }
    __syncthreads();
    const int j = tid & 63, fq = tid >> 6;
    for (int fo = 0; fo < 17; fo++) {
        int f = fo * 4 + fq;
        if (f > 64) continue;
        float wr = 0.f, wi = 0.f;
        int a = 0;
        for (int tau = 0; tau < 128; tau++) {
            float w = wrow[j * 129 + tau];
            wr += w * ct[a];
            wi += w * st[a];
            a = (a + f) & 127;
        }
        bf16* base = Wm + ((size_t)f * 128 + 2 * o) * 128 + 2 * j;
        base[0]   = (bf16)wr;
        base[1]   = (bf16)(-wi);
        base[128] = (bf16)wi;
        base[129] = (bf16)wr;
    }
}

// ---------------- K1: DFT of x-blocks ----------------
__global__ __launch_bounds__(256) void k1_dft(const float* __restrict__ x,
                                              const float* __restrict__ D,
                                              const bf16* __restrict__ B1,
                                              bf16* __restrict__ X) {
    __shared__ bf16 xs[8][16][136];
    const int tid = threadIdx.x;
    const int wave = tid >> 6, lane = tid & 63;
    const int q = lane >> 4, nl = lane & 15;
    const int s_t = blockIdx.x >> 1, jh = blockIdx.x & 1;
    const int s0 = s_t * 16;

    bf16x8 bfrag[3][4];
#pragma unroll
    for (int t = 0; t < 3; t++) {
        int nt = wave + 4 * t;
#pragma unroll
        for (int kc = 0; kc < 4; kc++)
            bfrag[t][kc] = *(const bf16x8*)(B1 + (nt * 16 + nl) * 128 + kc * 32 + q * 8);
    }

    for (int grp = 0; grp < 4; grp++) {
        const int jb = jh * 32 + grp * 8;
        __syncthreads();
        {   // stage 8 j-blocks x 16 s-rows, coalesced: 32 lanes per 512B row-segment
            const int l32 = tid & 31;
#pragma unroll
            for (int it = 0; it < 16; ++it) {
                int seg = it * 8 + (tid >> 5);       // 0..127
                int jl = seg >> 4, ss = seg & 15;
                const float* xp = x + (size_t)(s0 + ss) * 8192 + (jb + jl) * 128 + l32 * 4;
                const float* dp = D + (jb + jl) * 128 + l32 * 4;
                float4 a = *(const float4*)xp;
                float4 d = *(const float4*)dp;
                bf16x4 ov;
                ov[0] = (bf16)(a.x * d.x); ov[1] = (bf16)(a.y * d.y);
                ov[2] = (bf16)(a.z * d.z); ov[3] = (bf16)(a.w * d.w);
                *(bf16x4*)&xs[jl][ss][l32 * 4] = ov;
            }
        }
        __syncthreads();

        f32x4 acc[3][8];
        const f32x4 zero = {0.f, 0.f, 0.f, 0.f};
#pragma unroll
        for (int t = 0; t < 3; t++)
#pragma unroll
            for (int j = 0; j < 8; j++) acc[t][j] = zero;

#pragma unroll
        for (int j = 0; j < 8; j++) {
#pragma unroll
            for (int kc = 0; kc < 4; kc++) {
                bf16x8 a = *(const bf16x8*)&xs[j][nl][kc * 32 + q * 8];
#pragma unroll
                for (int t = 0; t < 3; t++)
                    acc[t][j] = __builtin_amdgcn_mfma_f32_16x16x32_bf16(
                        a, bfrag[t][kc], acc[t][j], 0, 0, 0);
            }
        }

        const int par = lane & 1;
#pragma unroll
        for (int t = 0; t < 3; t++) {
            const int fc = (wave + 4 * t) * 16 + nl;
            const int fpr = fc >> 1;
            const bool wr = (fc < 130);
#pragma unroll
            for (int r = 0; r < 4; r++) {
                float sh[8];
#pragma unroll
                for (int j = 0; j < 8; j++)
                    sh[j] = __shfl_xor(acc[t][j][r], 1);
                unsigned int d0, d1, d2, d3;
                if (!par) {
                    d0 = pack_bf2(acc[t][0][r], sh[0]);
                    d1 = pack_bf2(acc[t][1][r], sh[1]);
                    d2 = pack_bf2(acc[t][2][r], sh[2]);
                    d3 = pack_bf2(acc[t][3][r], sh[3]);
                } else {
                    d0 = pack_bf2(sh[4], acc[t][4][r]);
                    d1 = pack_bf2(sh[5], acc[t][5][r]);
                    d2 = pack_bf2(sh[6], acc[t][6][r]);
                    d3 = pack_bf2(sh[7], acc[t][7][r]);
                }
                if (wr) {
                    char* p = (char*)X + ((size_t)fpr * 4096 + s0 + q * 4 + r) * 256
                              + jb * 4 + par * 16;
                    *(uint4*)p = make_uint4(d0, d1, d2, d3);
                }
            }
        }
    }
}

// ---------------- K2a: per-frequency contraction ----------------
// grid 2176: blockIdx = (fg*4 + oc_t)*32 + s_t. 4 f per block, oc-tile 32,
// s-tile 128 (one 32-s slice per wave). Packs fc groups of 8 -> 16B Y stores.
__global__ __launch_bounds__(256) void k2a_freq(const bf16* __restrict__ X,
                                                const bf16* __restrict__ Wmat,
                                                bf16* __restrict__ Y) {
    __shared__ bf16 sA[128 * 136];
    const int tid = threadIdx.x;
    const int wave = tid >> 6, lane = tid & 63;
    const int q = lane >> 4, nl = lane & 15;
    const int b = blockIdx.x;
    const int s_t = b & 31, oc_t = (b >> 5) & 3, fg = b >> 7;
    const int oc0 = oc_t * 32;
    const int sbase = s_t * 128 + wave * 32;

    // stage Wmat[fg] oc-slice: rows [f_local*32 + oc_l][128 jc], pad 136
#pragma unroll
    for (int it = 0; it < 8; ++it) {
        int i = it * 256 + tid;
        int row = i >> 4, pos = i & 15;
        int f = fg * 4 + (row >> 5);
        if (f < 65) {
            *(uint4*)&sA[row * 136 + pos * 8] =
                *(const uint4*)(Wmat + ((size_t)f * 128 + oc0 + (row & 31)) * 128 + pos * 8);
        }
    }
    __syncthreads();

    f32x4 acc[4][2][2];
    const f32x4 zero = {0.f, 0.f, 0.f, 0.f};
#pragma unroll
    for (int F = 0; F < 4; F++)
#pragma unroll
        for (int m = 0; m < 2; m++)
#pragma unroll
            for (int n = 0; n < 2; n++) acc[F][m][n] = zero;

#pragma unroll
    for (int F = 0; F < 4; F++) {
        const int f = fg * 4 + F;
        if (f < 65) {
#pragma unroll
            for (int kc = 0; kc < 4; kc++) {
                bf16x8 bfr[2];
#pragma unroll
                for (int n = 0; n < 2; n++)
                    bfr[n] = *(const bf16x8*)(X + ((size_t)f * 4096 + sbase + n * 16 + nl) * 128
                                              + kc * 32 + q * 8);
#pragma unroll
                for (int m = 0; m < 2; m++) {
                    bf16x8 afr = *(const bf16x8*)&sA[(F * 32 + m * 16 + nl) * 136 + kc * 32 + q * 8];
#pragma unroll
                    for (int n = 0; n < 2; n++)
                        acc[F][m][n] = __builtin_amdgcn_mfma_f32_16x16x32_bf16(
                            afr, bfr[n], acc[F][m][n], 0, 0, 0);
                }
            }
        }
    }

    // pack 8 contiguous fc per lane, 16-B stores
#pragma unroll
    for (int m = 0; m < 2; m++) {
#pragma unroll
        for (int n = 0; n < 2; n++) {
            const int s = sbase + n * 16 + nl;
#pragma unroll
            for (int p = 0; p < 2; p++) {
                const int o = oc_t * 16 + m * 8 + q * 2 + p;
                bf16x8 v;
#pragma unroll
                for (int F = 0; F < 4; F++) {
                    v[2 * F]     = (bf16)acc[F][m][n][2 * p];
                    v[2 * F + 1] = (bf16)acc[F][m][n][2 * p + 1];
                }
                *(bf16x8*)(Y + ((size_t)s * 64 + o) * 160 + fg * 8) = v;
            }
        }
    }
}

// ---------------- K2b: inverse DFT GEMM ----------------
// out[row][t] = sum_fc Y[row][fc] * B2T[t][fc], row = s*64+o maps onto out rows.
// grid 1024: 256 rows/block, wave owns 64 rows x 128 t.
__global__ __launch_bounds__(256) void k2b_idft(const bf16* __restrict__ Y,
                                                const bf16* __restrict__ B2T,
                                                float* __restrict__ out) {
    __shared__ bf16 sB[128 * 168];
    const int tid = threadIdx.x;
    const int wave = tid >> 6, lane = tid & 63;
    const int q = lane >> 4, nl = lane & 15;
    const size_t r0 = (size_t)blockIdx.x * 256;

    for (int i = tid; i < 2560; i += 256) {
        int row = i / 20, pos = i - row * 20;
        *(uint4*)&sB[row * 168 + pos * 8] = *(const uint4*)(B2T + row * 160 + pos * 8);
    }
    __syncthreads();

    f32x4 acc[4][8];
    const f32x4 zero = {0.f, 0.f, 0.f, 0.f};
#pragma unroll
    for (int m = 0; m < 4; m++)
#pragma unroll
        for (int n = 0; n < 8; n++) acc[m][n] = zero;

    const size_t rbase = r0 + wave * 64 + nl;
#pragma unroll
    for (int kc = 0; kc < 5; kc++) {
        bf16x8 af[4];
#pragma unroll
        for (int m = 0; m < 4; m++)
            af[m] = *(const bf16x8*)(Y + (rbase + m * 16) * 160 + kc * 32 + q * 8);
#pragma unroll
        for (int n = 0; n < 8; n++) {
            bf16x8 bf = *(const bf16x8*)&sB[(n * 16 + nl) * 168 + kc * 32 + q * 8];
#pragma unroll
            for (int m = 0; m < 4; m++)
                acc[m][n] = __builtin_amdgcn_mfma_f32_16x16x32_bf16(af[m], bf, acc[m][n], 0, 0, 0);
        }
    }

#pragma unroll
    for (int m = 0; m < 4; m++) {
        const size_t row = r0 + wave * 64 + m * 16 + q * 4;
#pragma unroll
        for (int n = 0; n < 8; n++) {
            float* op = out + row * 128 + n * 16 + nl;
#pragma unroll
            for (int r = 0; r < 4; r++)
                op[(size_t)r * 128] = acc[m][n][r];
        }
    }
}

// ---------------- fallback fused K2 (used only if ws too small) ----------------
__global__ __launch_bounds__(256) void k2_gemm(const bf16* __restrict__ X,
                                               const bf16* __restrict__ Wmat,
                                               const bf16* __restrict__ B2T,
                                               float* __restrict__ out) {
    __shared__ bf16 ybuf[8 * 16 * 136 + 32];
    const int tid = threadIdx.x;
    const int wave = tid >> 6, lane = tid & 63;
    const int q = lane >> 4, nl = lane & 15;
    const int s_t = blockIdx.x >> 3, o_t = blockIdx.x & 7;
    const int s0 = s_t * 16;

    {
        unsigned int* yz = (unsigned int*)ybuf;
        for (int i = tid; i < (8 * 16 * 136 + 32) / 2; i += 256) yz[i] = 0u;
    }
    __syncthreads();

    for (int grp = 0; grp < 17; grp++) {
        const int f = grp * 4 + wave;
        if (f < 65) {
            f32x4 acc = {0.f, 0.f, 0.f, 0.f};
#pragma unroll
            for (int kc = 0; kc < 4; kc++) {
                bf16x8 a = *(const bf16x8*)(Wmat + ((size_t)f * 128 + o_t * 16 + nl) * 128
                                            + kc * 32 + q * 8);
                bf16x8 b = *(const bf16x8*)(X + ((size_t)f * 4096 + s0 + nl) * 128
                                            + kc * 32 + q * 8);
                acc = __builtin_amdgcn_mfma_f32_16x16x32_bf16(a, b, acc, 0, 0, 0);
            }
#pragma unroll
            for (int r = 0; r < 4; r++) {
                int oc = q * 4 + r;
                int o = oc >> 1, c = oc & 1;
                ybuf[(o * 16 + nl) * 136 + 2 * f + c] = (bf16)acc[r];
            }
        }
    }
    __syncthreads();

    for (int p = wave; p < 64; p += 4) {
        const int o = p >> 3, nt = p & 7;
        f32x4 acc = {0.f, 0.f, 0.f, 0.f};
#pragma unroll
        for (int kc = 0; kc < 5; kc++) {
            bf16x8 a = *(const bf16x8*)&ybuf[(o * 16 + nl) * 136 + kc * 32 + q * 8];
            bf16x8 b = *(const bf16x8*)(B2T + (nt * 16 + nl) * 160 + kc * 32 + q * 8);
            acc = __builtin_amdgcn_mfma_f32_16x16x32_bf16(a, b, acc, 0, 0, 0);
        }
        float* op = out + (size_t)(s0 + q * 4) * 8192 + (o_t * 8 + o) * 128 + nt * 16 + nl;
#pragma unroll
        for (int r = 0; r < 4; r++)
            op[(size_t)r * 8192] = acc[r];
    }
}

extern "C" void kernel_launch(void* const* d_in, const int* in_sizes, int n_in,
                              void* d_out, int out_size, void* d_ws, size_t ws_size,
                              hipStream_t stream) {
    const float* x = (const float*)d_in[0];
    const float* W = (const float*)d_in[1];
    const float* D = (const float*)d_in[2];
    float* out = (float*)d_out;
    char* ws = (char*)d_ws;
    bf16* B1  = (bf16*)(ws + WS_B1);
    bf16* B2T = (bf16*)(ws + WS_B2T);
    bf16* Wm  = (bf16*)(ws + WS_WMAT);
    bf16* X   = (bf16*)(ws + WS_X);
    bf16* Y   = (bf16*)(ws + WS_Y);

    hipLaunchKernelGGL(init_basis, dim3(96), dim3(256), 0, stream, B1, B2T);
    hipLaunchKernelGGL(init_wmat, dim3(64), dim3(256), 0, stream, W, Wm);
    hipLaunchKernelGGL(k1_dft, dim3(512), dim3(256), 0, stream, x, D, B1, X);
    if (ws_size >= WS_NEED) {
        hipLaunchKernelGGL(k2a_freq, dim3(2176), dim3(256), 0, stream, X, Wm, Y);
        hipLaunchKernelGGL(k2b_idft, dim3(1024), dim3(256), 0, stream, Y, B2T, out);
    } else {
        hipLaunchKernelGGL(k2_gemm, dim3(2048), dim3(256), 0, stream, X, Wm, B2T, out);
    }
}